// Round 8
// baseline (162.194 us; speedup 1.0000x reference)
//
#include <hip/hip_runtime.h>

#define BATCH 1024
#define DIM 128
#define MNBR 200
#define PAD_IDX 100000
#define LN_EPS 1e-5f

__device__ __forceinline__ float waveReduceSum(float v) {
    #pragma unroll
    for (int off = 32; off > 0; off >>= 1) v += __shfl_xor(v, off, 64);
    return v;
}

// One block per b, 512 threads, both sides. Single launch, no workspace.
__global__ __launch_bounds__(512, 8) void ee_kernel(
    const int* __restrict__ entity,
    const int* __restrict__ conn_left, const int* __restrict__ conn_right,
    const float* __restrict__ emb,
    const float* __restrict__ W_bil, const float* __restrict__ W_tail,
    const float* __restrict__ W_head,
    const float* __restrict__ gamma, const float* __restrict__ beta,
    float* __restrict__ out)
{
    __shared__ float wr[DIM], h0s[DIM], h1s[DIM];
    __shared__ float vp[2][DIM];
    __shared__ float hh[2][DIM];
    __shared__ int2  cidx[2][MNBR];
    __shared__ float accp[16][DIM];
    __shared__ float lp[16];
    __shared__ float agg[2][DIM];
    __shared__ float x[2][DIM];
    __shared__ float redS[8], redQ[8];

    const int b   = blockIdx.x;
    const int tid = threadIdx.x;
    const int g   = tid >> 5;     // 16 half-waves
    const int l   = tid & 31;

    // ---- Phase A: head rows (tid<128) || conn preload for both sides ----
    if (tid < DIM) {
        const int e0 = entity[b * 2 + 0], e1 = entity[b * 2 + 1];
        const float hl = emb[(size_t)e0 * DIM + tid];
        const float hr = emb[(size_t)e1 * DIM + tid];
        wr[tid] = hr - hl; h0s[tid] = hl; h1s[tid] = hr;
    } else if (tid < 128 + 100) {           // side 0: conn_left, 100 x int4 = 200 nbrs
        const int t = tid - 128;
        const int4 c = *reinterpret_cast<const int4*>(conn_left + (size_t)b * MNBR * 2 + t * 4);
        cidx[0][t * 2 + 0] = make_int2(c.x, c.y);
        cidx[0][t * 2 + 1] = make_int2(c.z, c.w);
    } else if (tid < 128 + 200) {           // side 1: conn_right
        const int t = tid - 228;
        const int4 c = *reinterpret_cast<const int4*>(conn_right + (size_t)b * MNBR * 2 + t * 4);
        cidx[1][t * 2 + 0] = make_int2(c.x, c.y);
        cidx[1][t * 2 + 1] = make_int2(c.z, c.w);
    }
    __syncthreads();

    // ---- Phase B (wave-specialized, concurrent W_bil and W_head streams) ----
    if (tid < 256) {
        // waves 0-7: v partials, 2-way split over d
        const int e = tid & 127, part = tid >> 7;
        float acc = 0.f;
        const int d0 = part * 64;
        #pragma unroll 8
        for (int d = d0; d < d0 + 64; ++d)
            acc += wr[d] * W_bil[(size_t)d * DIM + e];
        vp[part][e] = acc;
    } else {
        // waves 8-15: hh for both sides, sharing one W_head stream
        const int t2 = tid & 255;
        const int g2 = t2 >> 5;             // 0..7
        const float4 a4 = *reinterpret_cast<const float4*>(&h0s[l * 4]);
        const float4 b4 = *reinterpret_cast<const float4*>(&h1s[l * 4]);
        #pragma unroll
        for (int i = 0; i < 16; ++i) {
            const int e = g2 * 16 + i;
            const float4 wh = *reinterpret_cast<const float4*>(W_head + (size_t)e * DIM + l * 4);
            float d0 = a4.x * wh.x + a4.y * wh.y + a4.z * wh.z + a4.w * wh.w;
            float d1 = b4.x * wh.x + b4.y * wh.y + b4.z * wh.z + b4.w * wh.w;
            #pragma unroll
            for (int off = 16; off > 0; off >>= 1) {
                d0 += __shfl_xor(d0, off, 64);
                d1 += __shfl_xor(d1, off, 64);
            }
            if (l == 0) { hh[0][e] = d0; hh[1][e] = d1; }
        }
    }
    __syncthreads();

    // ---- Gather: half-wave g -> side g>>3, contiguous chunk of 25 neighbors ----
    {
        const int side  = g >> 3;
        const int m0    = (g & 7) * 25;
        const float4 va = *reinterpret_cast<const float4*>(&vp[0][l * 4]);
        const float4 vb = *reinterpret_cast<const float4*>(&vp[1][l * 4]);
        const float4 v4 = make_float4(va.x + vb.x, va.y + vb.y, va.z + vb.z, va.w + vb.w);
        const int2* ci  = cidx[side];
        float a0 = 0.f, a1 = 0.f, a2 = 0.f, a3 = 0.f, ls = 0.f;
        #pragma unroll 5
        for (int m = m0; m < m0 + 25; ++m) {
            const int rid = ci[m].x, eid = ci[m].y;
            const float4 r = *reinterpret_cast<const float4*>(emb + (size_t)rid * DIM + l * 4);
            const float4 t = *reinterpret_cast<const float4*>(emb + (size_t)eid * DIM + l * 4);
            float dot = v4.x * r.x + v4.y * r.y + v4.z * r.z + v4.w * r.w;
            #pragma unroll
            for (int off = 16; off > 0; off >>= 1) dot += __shfl_xor(dot, off, 64);
            const float p = (rid == PAD_IDX) ? 0.f : __expf(dot);
            ls += p;
            a0 = fmaf(p, t.x, a0); a1 = fmaf(p, t.y, a1);
            a2 = fmaf(p, t.z, a2); a3 = fmaf(p, t.w, a3);
        }
        *reinterpret_cast<float4*>(&accp[g][l * 4]) = make_float4(a0, a1, a2, a3);
        if (l == 0) lp[g] = ls;
    }
    __syncthreads();

    // ---- Combine partials per side (pure LDS; no global loads) ----
    if (tid < 256) {
        const int s = tid >> 7, d = tid & 127;
        const int gb = s * 8;
        float lt = 0.f, a = 0.f;
        #pragma unroll
        for (int i = 0; i < 8; ++i) { lt += lp[gb + i]; a += accp[gb + i][d]; }
        agg[s][d] = a / lt;
    }
    __syncthreads();

    // ---- Dual-side W_tail matvec + relu + residual ----
    {
        const float4 a0v = *reinterpret_cast<const float4*>(&agg[0][l * 4]);
        const float4 a1v = *reinterpret_cast<const float4*>(&agg[1][l * 4]);
        #pragma unroll
        for (int i = 0; i < 8; ++i) {
            const int e = g + i * 16;
            const float4 wt = *reinterpret_cast<const float4*>(W_tail + (size_t)e * DIM + l * 4);
            float d0 = a0v.x * wt.x + a0v.y * wt.y + a0v.z * wt.z + a0v.w * wt.w;
            float d1 = a1v.x * wt.x + a1v.y * wt.y + a1v.z * wt.z + a1v.w * wt.w;
            #pragma unroll
            for (int off = 16; off > 0; off >>= 1) {
                d0 += __shfl_xor(d0, off, 64);
                d1 += __shfl_xor(d1, off, 64);
            }
            if (l == 0) {
                x[0][e] = fmaxf(d0 + hh[0][e], 0.f) + h0s[e];
                x[1][e] = fmaxf(d1 + hh[1][e], 0.f) + h1s[e];
            }
        }
    }
    __syncthreads();

    // ---- Single-pass dual LayerNorm + store ----
    {
        const int s = tid >> 8;
        const int d = tid & 255;
        const int w = tid >> 6;           // wave id 0..7
        float xv = 0.f;
        if (d < DIM) xv = x[s][d];
        float sum = waveReduceSum(xv);
        float sq  = waveReduceSum(xv * xv);
        if ((tid & 63) == 0) { redS[w] = sum; redQ[w] = sq; }
        __syncthreads();
        if (d < DIM) {
            const float tS = redS[s * 4] + redS[s * 4 + 1];
            const float tQ = redQ[s * 4] + redQ[s * 4 + 1];
            const float mean = tS * (1.f / DIM);
            const float var  = tQ * (1.f / DIM) - mean * mean;
            out[(size_t)s * BATCH * DIM + (size_t)b * DIM + d] =
                (xv - mean) * rsqrtf(var + LN_EPS) * gamma[d] + beta[d];
        }
    }
}

extern "C" void kernel_launch(void* const* d_in, const int* in_sizes, int n_in,
                              void* d_out, int out_size, void* d_ws, size_t ws_size,
                              hipStream_t stream) {
    const int*   entity = (const int*)d_in[0];
    const int*   cl     = (const int*)d_in[1];
    const int*   cr     = (const int*)d_in[2];
    const float* emb    = (const float*)d_in[3];
    const float* W_bil  = (const float*)d_in[4];
    const float* W_tail = (const float*)d_in[5];
    const float* W_head = (const float*)d_in[6];
    const float* gamma  = (const float*)d_in[7];
    const float* beta   = (const float*)d_in[8];
    float* out = (float*)d_out;

    ee_kernel<<<BATCH, 512, 0, stream>>>(
        entity, cl, cr, emb, W_bil, W_tail, W_head, gamma, beta, out);
}

// Round 9
// 145.193 us; speedup vs baseline: 1.1171x; 1.1171x over previous
//
#include <hip/hip_runtime.h>
#include <hip/hip_bf16.h>

#define BATCH 1024
#define DIM 128
#define MNBR 200
#define PAD_IDX 100000
#define LN_EPS 1e-5f

typedef unsigned short ushort_t;
#define EMB_ELEMS ((size_t)(PAD_IDX + 1) * DIM)          // 12,800,128 (div by 8)
#define WS_NEED_BYTES (EMB_ELEMS * 2)

__device__ __forceinline__ float bf2f(ushort_t u) {
    union { unsigned int i; float f; } x;
    x.i = ((unsigned int)u) << 16;
    return x.f;
}
__device__ __forceinline__ ushort_t f2bf(float f) {
    __hip_bfloat16 h = __float2bfloat16(f);
    ushort_t u; __builtin_memcpy(&u, &h, 2); return u;
}

__device__ __forceinline__ float waveReduceSum(float v) {
    #pragma unroll
    for (int off = 32; off > 0; off >>= 1) v += __shfl_xor(v, off, 64);
    return v;
}

// ---------------- K0: emb fp32 -> bf16 into ws (streaming, RNE) ----------------
__global__ __launch_bounds__(256) void k0_convert(
    const float* __restrict__ emb, ushort_t* __restrict__ dst)
{
    const size_t i = ((size_t)blockIdx.x * 256 + threadIdx.x) * 8;
    if (i < EMB_ELEMS) {
        const float4 a = *reinterpret_cast<const float4*>(emb + i);
        const float4 b = *reinterpret_cast<const float4*>(emb + i + 4);
        uint4 o;
        o.x = (unsigned)f2bf(a.x) | ((unsigned)f2bf(a.y) << 16);
        o.y = (unsigned)f2bf(a.z) | ((unsigned)f2bf(a.w) << 16);
        o.z = (unsigned)f2bf(b.x) | ((unsigned)f2bf(b.y) << 16);
        o.w = (unsigned)f2bf(b.z) | ((unsigned)f2bf(b.w) << 16);
        *reinterpret_cast<uint4*>(dst + i) = o;
    }
}

// ---------------- Main: R7 structure, gather rows from bf16 table ----------------
__global__ __launch_bounds__(512, 8) void ee_kernel_bf(
    const int* __restrict__ entity,
    const int* __restrict__ conn_left, const int* __restrict__ conn_right,
    const float* __restrict__ emb, const ushort_t* __restrict__ embb,
    const float* __restrict__ W_bil, const float* __restrict__ W_tail,
    const float* __restrict__ W_head,
    const float* __restrict__ gamma, const float* __restrict__ beta,
    float* __restrict__ out)
{
    __shared__ float wr[DIM], h0s[DIM], h1s[DIM];
    __shared__ float vp[4][DIM];
    __shared__ float v[DIM];
    __shared__ float hh[2][DIM];
    __shared__ int2  cidx[2][MNBR];
    __shared__ float accp[16][DIM];
    __shared__ float lp[16];
    __shared__ float agg[2][DIM];
    __shared__ float x[2][DIM];
    __shared__ float redS[8], redQ[8];

    const int b   = blockIdx.x;
    const int tid = threadIdx.x;
    const int g   = tid >> 5;     // 16 half-waves
    const int l   = tid & 31;

    // ---- Phase A: head rows (tid<128, fp32) || conn preload for both sides ----
    if (tid < DIM) {
        const int e0 = entity[b * 2 + 0], e1 = entity[b * 2 + 1];
        const float hl = emb[(size_t)e0 * DIM + tid];
        const float hr = emb[(size_t)e1 * DIM + tid];
        wr[tid] = hr - hl; h0s[tid] = hl; h1s[tid] = hr;
    } else if (tid < 128 + 100) {
        const int t = tid - 128;
        const int4 c = *reinterpret_cast<const int4*>(conn_left + (size_t)b * MNBR * 2 + t * 4);
        cidx[0][t * 2 + 0] = make_int2(c.x, c.y);
        cidx[0][t * 2 + 1] = make_int2(c.z, c.w);
    } else if (tid < 128 + 200) {
        const int t = tid - 228;
        const int4 c = *reinterpret_cast<const int4*>(conn_right + (size_t)b * MNBR * 2 + t * 4);
        cidx[1][t * 2 + 0] = make_int2(c.x, c.y);
        cidx[1][t * 2 + 1] = make_int2(c.z, c.w);
    }
    __syncthreads();

    // ---- Phase B1: v partials, 4-way split over d ----
    {
        const int e = tid & 127, part = tid >> 7;
        float acc = 0.f;
        const int d0 = part * 32;
        #pragma unroll 8
        for (int d = d0; d < d0 + 32; ++d)
            acc += wr[d] * W_bil[(size_t)d * DIM + e];
        vp[part][e] = acc;
    }
    __syncthreads();

    // ---- Phase B2: v combine (tid<128) + dual-side hh (all threads) ----
    if (tid < DIM) v[tid] = (vp[0][tid] + vp[1][tid]) + (vp[2][tid] + vp[3][tid]);
    {
        const float4 a4 = *reinterpret_cast<const float4*>(&h0s[l * 4]);
        const float4 b4 = *reinterpret_cast<const float4*>(&h1s[l * 4]);
        #pragma unroll
        for (int i = 0; i < 8; ++i) {
            const int e = g + i * 16;
            const float4 wh = *reinterpret_cast<const float4*>(W_head + (size_t)e * DIM + l * 4);
            float d0 = a4.x * wh.x + a4.y * wh.y + a4.z * wh.z + a4.w * wh.w;
            float d1 = b4.x * wh.x + b4.y * wh.y + b4.z * wh.z + b4.w * wh.w;
            #pragma unroll
            for (int off = 16; off > 0; off >>= 1) {
                d0 += __shfl_xor(d0, off, 64);
                d1 += __shfl_xor(d1, off, 64);
            }
            if (l == 0) { hh[0][e] = d0; hh[1][e] = d1; }
        }
    }
    __syncthreads();

    // ---- Gather (bf16 rows): half-wave g -> side g>>3, chunk of 25 neighbors ----
    {
        const int side  = g >> 3;
        const int m0    = (g & 7) * 25;
        const float4 v4 = *reinterpret_cast<const float4*>(&v[l * 4]);
        const int2* ci  = cidx[side];
        float a0 = 0.f, a1 = 0.f, a2 = 0.f, a3 = 0.f, ls = 0.f;
        #pragma unroll 5
        for (int m = m0; m < m0 + 25; ++m) {
            const int rid = ci[m].x, eid = ci[m].y;
            const ushort4 ru = *reinterpret_cast<const ushort4*>(embb + (size_t)rid * DIM + l * 4);
            const ushort4 tu = *reinterpret_cast<const ushort4*>(embb + (size_t)eid * DIM + l * 4);
            float dot = v4.x * bf2f(ru.x) + v4.y * bf2f(ru.y)
                      + v4.z * bf2f(ru.z) + v4.w * bf2f(ru.w);
            #pragma unroll
            for (int off = 16; off > 0; off >>= 1) dot += __shfl_xor(dot, off, 64);
            const float p = (rid == PAD_IDX) ? 0.f : __expf(dot);
            ls += p;
            a0 = fmaf(p, bf2f(tu.x), a0); a1 = fmaf(p, bf2f(tu.y), a1);
            a2 = fmaf(p, bf2f(tu.z), a2); a3 = fmaf(p, bf2f(tu.w), a3);
        }
        *reinterpret_cast<float4*>(&accp[g][l * 4]) = make_float4(a0, a1, a2, a3);
        if (l == 0) lp[g] = ls;
    }
    __syncthreads();

    // ---- Combine partials per side ----
    if (tid < 256) {
        const int s = tid >> 7, d = tid & 127;
        const int gb = s * 8;
        float lt = 0.f, a = 0.f;
        #pragma unroll
        for (int i = 0; i < 8; ++i) { lt += lp[gb + i]; a += accp[gb + i][d]; }
        agg[s][d] = a / lt;
    }
    __syncthreads();

    // ---- Dual-side W_tail matvec + relu + residual ----
    {
        const float4 a0v = *reinterpret_cast<const float4*>(&agg[0][l * 4]);
        const float4 a1v = *reinterpret_cast<const float4*>(&agg[1][l * 4]);
        #pragma unroll
        for (int i = 0; i < 8; ++i) {
            const int e = g + i * 16;
            const float4 wt = *reinterpret_cast<const float4*>(W_tail + (size_t)e * DIM + l * 4);
            float d0 = a0v.x * wt.x + a0v.y * wt.y + a0v.z * wt.z + a0v.w * wt.w;
            float d1 = a1v.x * wt.x + a1v.y * wt.y + a1v.z * wt.z + a1v.w * wt.w;
            #pragma unroll
            for (int off = 16; off > 0; off >>= 1) {
                d0 += __shfl_xor(d0, off, 64);
                d1 += __shfl_xor(d1, off, 64);
            }
            if (l == 0) {
                x[0][e] = fmaxf(d0 + hh[0][e], 0.f) + h0s[e];
                x[1][e] = fmaxf(d1 + hh[1][e], 0.f) + h1s[e];
            }
        }
    }
    __syncthreads();

    // ---- Single-pass dual LayerNorm + store ----
    {
        const int s = tid >> 8;
        const int d = tid & 255;
        const int w = tid >> 6;
        float xv = 0.f;
        if (d < DIM) xv = x[s][d];
        float sum = waveReduceSum(xv);
        float sq  = waveReduceSum(xv * xv);
        if ((tid & 63) == 0) { redS[w] = sum; redQ[w] = sq; }
        __syncthreads();
        if (d < DIM) {
            const float tS = redS[s * 4] + redS[s * 4 + 1];
            const float tQ = redQ[s * 4] + redQ[s * 4 + 1];
            const float mean = tS * (1.f / DIM);
            const float var  = tQ * (1.f / DIM) - mean * mean;
            out[(size_t)s * BATCH * DIM + (size_t)b * DIM + d] =
                (xv - mean) * rsqrtf(var + LN_EPS) * gamma[d] + beta[d];
        }
    }
}

// ---------------- Fallback: R7 kernel verbatim (fp32 gather, no ws) ----------------
__global__ __launch_bounds__(512, 8) void ee_kernel_f32(
    const int* __restrict__ entity,
    const int* __restrict__ conn_left, const int* __restrict__ conn_right,
    const float* __restrict__ emb,
    const float* __restrict__ W_bil, const float* __restrict__ W_tail,
    const float* __restrict__ W_head,
    const float* __restrict__ gamma, const float* __restrict__ beta,
    float* __restrict__ out)
{
    __shared__ float wr[DIM], h0s[DIM], h1s[DIM];
    __shared__ float vp[4][DIM];
    __shared__ float v[DIM];
    __shared__ float hh[2][DIM];
    __shared__ int2  cidx[2][MNBR];
    __shared__ float accp[16][DIM];
    __shared__ float lp[16];
    __shared__ float agg[2][DIM];
    __shared__ float x[2][DIM];
    __shared__ float redS[8], redQ[8];

    const int b   = blockIdx.x;
    const int tid = threadIdx.x;
    const int g   = tid >> 5;
    const int l   = tid & 31;

    if (tid < DIM) {
        const int e0 = entity[b * 2 + 0], e1 = entity[b * 2 + 1];
        const float hl = emb[(size_t)e0 * DIM + tid];
        const float hr = emb[(size_t)e1 * DIM + tid];
        wr[tid] = hr - hl; h0s[tid] = hl; h1s[tid] = hr;
    } else if (tid < 128 + 100) {
        const int t = tid - 128;
        const int4 c = *reinterpret_cast<const int4*>(conn_left + (size_t)b * MNBR * 2 + t * 4);
        cidx[0][t * 2 + 0] = make_int2(c.x, c.y);
        cidx[0][t * 2 + 1] = make_int2(c.z, c.w);
    } else if (tid < 128 + 200) {
        const int t = tid - 228;
        const int4 c = *reinterpret_cast<const int4*>(conn_right + (size_t)b * MNBR * 2 + t * 4);
        cidx[1][t * 2 + 0] = make_int2(c.x, c.y);
        cidx[1][t * 2 + 1] = make_int2(c.z, c.w);
    }
    __syncthreads();
    {
        const int e = tid & 127, part = tid >> 7;
        float acc = 0.f;
        const int d0 = part * 32;
        #pragma unroll 8
        for (int d = d0; d < d0 + 32; ++d)
            acc += wr[d] * W_bil[(size_t)d * DIM + e];
        vp[part][e] = acc;
    }
    __syncthreads();
    if (tid < DIM) v[tid] = (vp[0][tid] + vp[1][tid]) + (vp[2][tid] + vp[3][tid]);
    {
        const float4 a4 = *reinterpret_cast<const float4*>(&h0s[l * 4]);
        const float4 b4 = *reinterpret_cast<const float4*>(&h1s[l * 4]);
        #pragma unroll
        for (int i = 0; i < 8; ++i) {
            const int e = g + i * 16;
            const float4 wh = *reinterpret_cast<const float4*>(W_head + (size_t)e * DIM + l * 4);
            float d0 = a4.x * wh.x + a4.y * wh.y + a4.z * wh.z + a4.w * wh.w;
            float d1 = b4.x * wh.x + b4.y * wh.y + b4.z * wh.z + b4.w * wh.w;
            #pragma unroll
            for (int off = 16; off > 0; off >>= 1) {
                d0 += __shfl_xor(d0, off, 64);
                d1 += __shfl_xor(d1, off, 64);
            }
            if (l == 0) { hh[0][e] = d0; hh[1][e] = d1; }
        }
    }
    __syncthreads();
    {
        const int side  = g >> 3;
        const int m0    = (g & 7) * 25;
        const float4 v4 = *reinterpret_cast<const float4*>(&v[l * 4]);
        const int2* ci  = cidx[side];
        float a0 = 0.f, a1 = 0.f, a2 = 0.f, a3 = 0.f, ls = 0.f;
        #pragma unroll 5
        for (int m = m0; m < m0 + 25; ++m) {
            const int rid = ci[m].x, eid = ci[m].y;
            const float4 r = *reinterpret_cast<const float4*>(emb + (size_t)rid * DIM + l * 4);
            const float4 t = *reinterpret_cast<const float4*>(emb + (size_t)eid * DIM + l * 4);
            float dot = v4.x * r.x + v4.y * r.y + v4.z * r.z + v4.w * r.w;
            #pragma unroll
            for (int off = 16; off > 0; off >>= 1) dot += __shfl_xor(dot, off, 64);
            const float p = (rid == PAD_IDX) ? 0.f : __expf(dot);
            ls += p;
            a0 = fmaf(p, t.x, a0); a1 = fmaf(p, t.y, a1);
            a2 = fmaf(p, t.z, a2); a3 = fmaf(p, t.w, a3);
        }
        *reinterpret_cast<float4*>(&accp[g][l * 4]) = make_float4(a0, a1, a2, a3);
        if (l == 0) lp[g] = ls;
    }
    __syncthreads();
    if (tid < 256) {
        const int s = tid >> 7, d = tid & 127;
        const int gb = s * 8;
        float lt = 0.f, a = 0.f;
        #pragma unroll
        for (int i = 0; i < 8; ++i) { lt += lp[gb + i]; a += accp[gb + i][d]; }
        agg[s][d] = a / lt;
    }
    __syncthreads();
    {
        const float4 a0v = *reinterpret_cast<const float4*>(&agg[0][l * 4]);
        const float4 a1v = *reinterpret_cast<const float4*>(&agg[1][l * 4]);
        #pragma unroll
        for (int i = 0; i < 8; ++i) {
            const int e = g + i * 16;
            const float4 wt = *reinterpret_cast<const float4*>(W_tail + (size_t)e * DIM + l * 4);
            float d0 = a0v.x * wt.x + a0v.y * wt.y + a0v.z * wt.z + a0v.w * wt.w;
            float d1 = a1v.x * wt.x + a1v.y * wt.y + a1v.z * wt.z + a1v.w * wt.w;
            #pragma unroll
            for (int off = 16; off > 0; off >>= 1) {
                d0 += __shfl_xor(d0, off, 64);
                d1 += __shfl_xor(d1, off, 64);
            }
            if (l == 0) {
                x[0][e] = fmaxf(d0 + hh[0][e], 0.f) + h0s[e];
                x[1][e] = fmaxf(d1 + hh[1][e], 0.f) + h1s[e];
            }
        }
    }
    __syncthreads();
    {
        const int s = tid >> 8;
        const int d = tid & 255;
        const int w = tid >> 6;
        float xv = 0.f;
        if (d < DIM) xv = x[s][d];
        float sum = waveReduceSum(xv);
        float sq  = waveReduceSum(xv * xv);
        if ((tid & 63) == 0) { redS[w] = sum; redQ[w] = sq; }
        __syncthreads();
        if (d < DIM) {
            const float tS = redS[s * 4] + redS[s * 4 + 1];
            const float tQ = redQ[s * 4] + redQ[s * 4 + 1];
            const float mean = tS * (1.f / DIM);
            const float var  = tQ * (1.f / DIM) - mean * mean;
            out[(size_t)s * BATCH * DIM + (size_t)b * DIM + d] =
                (xv - mean) * rsqrtf(var + LN_EPS) * gamma[d] + beta[d];
        }
    }
}

extern "C" void kernel_launch(void* const* d_in, const int* in_sizes, int n_in,
                              void* d_out, int out_size, void* d_ws, size_t ws_size,
                              hipStream_t stream) {
    const int*   entity = (const int*)d_in[0];
    const int*   cl     = (const int*)d_in[1];
    const int*   cr     = (const int*)d_in[2];
    const float* emb    = (const float*)d_in[3];
    const float* W_bil  = (const float*)d_in[4];
    const float* W_tail = (const float*)d_in[5];
    const float* W_head = (const float*)d_in[6];
    const float* gamma  = (const float*)d_in[7];
    const float* beta   = (const float*)d_in[8];
    float* out = (float*)d_out;

    if (ws_size >= WS_NEED_BYTES) {
        ushort_t* embb = (ushort_t*)d_ws;
        const int nblk = (int)((EMB_ELEMS / 8 + 255) / 256);
        k0_convert<<<nblk, 256, 0, stream>>>(emb, embb);
        ee_kernel_bf<<<BATCH, 512, 0, stream>>>(
            entity, cl, cr, emb, embb, W_bil, W_tail, W_head, gamma, beta, out);
    } else {
        ee_kernel_f32<<<BATCH, 512, 0, stream>>>(
            entity, cl, cr, emb, W_bil, W_tail, W_head, gamma, beta, out);
    }
}